// Round 10
// baseline (123.997 us; speedup 1.0000x reference)
//
#include <hip/hip_runtime.h>

// HungarianMatcher cost matrix: C[n,t] = 5*L1(box_n,box_t) + 2*(pos-neg)[n,id_t] - 2*GIoU(n,t)
// bs=16, nq=900 -> N=14400 rows; T=1600 targets; nc=91 classes.
// R10: PERSISTENT blocks (450 blocks x 2 row-groups, grid-stride) + pipelined
// prologue. Evidence: R8's marginal warm pass ~29us (near the ~22us roofline)
// vs first pass ~43us -> steady loop is fine; ~15us is per-block startup paid
// ~3.5x serially per CU. Persistence pays t-data/corners ONCE per block and
// hides group g+1's logits load under group g's row loop (double-buffered
// transposed tab, one barrier per group).
// Kept from R9 (best, 120.5): plain stores, per-thread tv[4][4] register
// prefetch of the 4 row-invariant class columns, block-uniform pbox s_loads.
// Predicted: matcher ~43 -> ~36, dur 120.5 -> ~112-115. Neutral -> declare
// structural ceiling (steady state at roofline; rest is harness floor).

#define NC 91
#define TT 1600
#define T4 (TT / 4)         // 400 float4 columns
#define ROWS 16
#define RPAD 20             // padded row-dim: 80B stride, 16B-aligned
#define NTHREADS 448
#define TABN (ROWS * NC)    // 1456 logical floats per group
#define TAB4 (TABN / 4)     // 364 float4 loads per group

typedef float vfloat4 __attribute__((ext_vector_type(4)));

__device__ __forceinline__ float focal_tab(float x) {
    const float p = __builtin_amdgcn_rcpf(1.f + __expf(-x));  // sigmoid
    const float omp = 1.f - p;
    const float neg = 0.75f * p * p * (-__logf(omp + 1e-8f));
    const float pos = 0.25f * omp * omp * (-__logf(p + 1e-8f));
    return 2.f * (pos - neg) + 2.f;   // fold COST_CLASS and giou's "+1"
}

__device__ __forceinline__ void focal_to_tab(float* tabbuf, int tid, float4 v) {
    const float vv[4] = {v.x, v.y, v.z, v.w};
#pragma unroll
    for (int k = 0; k < 4; ++k) {
        const int e = 4 * tid + k;      // flat [16][91] element
        const int r = e / NC;           // magic-mul div
        const int c = e - r * NC;
        tabbuf[c * RPAD + r] = focal_tab(vv[k]);  // transposed [class][row]
    }
}

__global__ __launch_bounds__(NTHREADS, 4) void matcher_kernel(
    const float* __restrict__ logits,      // [N, 91]
    const float4* __restrict__ pboxes,     // [N] (cx,cy,w,h)
    const int4* __restrict__ tids,         // [T/4]
    const float4* __restrict__ tboxes,     // [T] (cx,cy,w,h)
    vfloat4* __restrict__ out,             // [N, T/4]
    int ngroups)                           // N / ROWS
{
    __shared__ __align__(16) float tab[2][NC * RPAD];  // double-buffered

    const int tid = threadIdx.x;
    const bool active = (tid < T4);
    const bool ftab = (tid < TAB4);

    // --- once per BLOCK: t-side data + corners (amortized over all groups) ---
    int4 ids = {0, 0, 0, 0};
    float4 tb[4];
    if (active) {
        ids = tids[tid];
#pragma unroll
        for (int j = 0; j < 4; ++j) tb[j] = tboxes[tid * 4 + j];
    }

    // first group's logits -> tab[0] (latency overlaps corner math below)
    const int g0 = blockIdx.x;
    float4 lg;
    if (ftab)
        lg = *reinterpret_cast<const float4*>(
            logits + (size_t)g0 * ROWS * NC + 4 * (size_t)tid);

    const int idv[4] = {ids.x, ids.y, ids.z, ids.w};
    float tx0[4], ty0[4], tx1[4], ty1[4];
#pragma unroll
    for (int j = 0; j < 4; ++j) {
        tx0[j] = tb[j].x - 0.5f * tb[j].z;
        ty0[j] = tb[j].y - 0.5f * tb[j].w;
        tx1[j] = tb[j].x + 0.5f * tb[j].z;
        ty1[j] = tb[j].y + 0.5f * tb[j].w;
    }

    if (ftab) focal_to_tab(tab[0], tid, lg);

    int buf = 0;
    for (int g = g0; g < ngroups; g += gridDim.x) {
        __syncthreads();                 // tab[buf] ready for ALL threads

        // pipeline: issue NEXT group's logits load now; consumed after the
        // row loop (latency hides under 16 rows of compute + stores)
        const int gn = g + gridDim.x;
        float4 lgn;
        if (gn < ngroups && ftab)
            lgn = *reinterpret_cast<const float4*>(
                logits + (size_t)gn * ROWS * NC + 4 * (size_t)tid);

        if (active) {
            // prefetch this thread's 4 row-invariant class columns: 16x
            // ds_read_b128 -> 64 VGPRs; main loop then has NO LDS traffic
            vfloat4 tv[4][4];
#pragma unroll
            for (int j = 0; j < 4; ++j)
#pragma unroll
                for (int q = 0; q < 4; ++q)
                    tv[j][q] = *reinterpret_cast<const vfloat4*>(
                        &tab[buf][idv[j] * RPAD + 4 * q]);

            const int n0 = g * ROWS;
#pragma unroll
            for (int r = 0; r < ROWS; ++r) {
                const float4 b = pboxes[n0 + r];   // block-uniform -> s_load
                const float pcx = b.x, pcy = b.y, pw = b.z, ph = b.w;
                const float px0 = pcx - 0.5f * pw, py0 = pcy - 0.5f * ph;
                const float px1 = pcx + 0.5f * pw, py1 = pcy + 0.5f * ph;
                const float pa  = pw * ph;
                vfloat4 res;
#pragma unroll
                for (int j = 0; j < 4; ++j) {
                    const float tw = tx1[j] - tx0[j];
                    const float th = ty1[j] - ty0[j];
                    const float iwr = fminf(px1, tx1[j]) - fmaxf(px0, tx0[j]);
                    const float ihr = fminf(py1, ty1[j]) - fmaxf(py0, ty0[j]);
                    const float inter = fmaxf(iwr, 0.f) * fmaxf(ihr, 0.f);
                    const float uni = pa + tw * th - inter;
                    const float ew = (pw + tw) - iwr;   // min+max identity
                    const float eh = (ph + th) - ihr;
                    const float ae = ew * eh;
                    const float tcx = tx0[j] + 0.5f * tw;
                    const float tcy = ty0[j] + 0.5f * th;
                    const float l1 = fabsf(pcx - tcx) + fabsf(pcy - tcy)
                                   + fabsf(pw - tw) + fabsf(ph - th);
                    res[j] = 5.f * l1 + tv[j][r >> 2][r & 3]
                           - 2.f * inter * __builtin_amdgcn_rcpf(uni)
                           - 2.f * uni * __builtin_amdgcn_rcpf(ae);
                }
                out[(size_t)(n0 + r) * T4 + tid] = res;
            }
        }

        // finish the pipeline: focal for the next group into the other buffer
        if (gn < ngroups && ftab) focal_to_tab(tab[buf ^ 1], tid, lgn);
        buf ^= 1;
    }
}

extern "C" void kernel_launch(void* const* d_in, const int* in_sizes, int n_in,
                              void* d_out, int out_size, void* d_ws, size_t ws_size,
                              hipStream_t stream) {
    const float* logits  = (const float*)d_in[0];
    const float4* pboxes = (const float4*)d_in[1];
    const int4* tids     = (const int4*)d_in[2];
    const float4* tboxes = (const float4*)d_in[3];
    vfloat4* out = (vfloat4*)d_out;
    const int N = in_sizes[1] / 4;          // 14400 rows
    const int ngroups = N / ROWS;           // 900
    const int nblocks = (ngroups + 1) / 2;  // 450: persistent, G=2 each
    matcher_kernel<<<nblocks, NTHREADS, 0, stream>>>(logits, pboxes, tids,
                                                     tboxes, out, ngroups);
}